// Round 4
// baseline (373.045 us; speedup 1.0000x reference)
//
#include <hip/hip_runtime.h>
#include <hip/hip_bf16.h>
#include <stdint.h>

// NODE forest — MFMA path, round 3 (resubmit: r3 bench hit GPUAcquisitionTimeout,
// kernel never executed — no evidence to update on).
// r1/r2 verified: 48 per-row selector dots as bf16-split GEMM on the matrix
// pipe (hi+lo, 3 product terms kept, lo.lo dropped), np-exact fixup for
// near-threshold logits. PASS, absmax 0.0078125 (numpy-bit-exact invariant).
// r3 changes:
//   1. margin 2e-3 -> 8e-4. Analytic worst-case drift of the bf16-split vs
//      numpy f32 order: 3*2^-18 * max Sum|x_i w_i| (~10 at 6-sigma) ~= 1.1e-4,
//      + ~2e-6 accumulation rounding. 8e-4 is 7x worst-case, >30x realistic.
//      Flag rate drops ~2.5x -> wave-max fixup iterations ~2 -> ~1.
//   2. 128 rows per wave (2048 blocks x 4 waves): W load+convert (~600cyc),
//      taub, lleaf staging amortized over 2x rows; xa becomes a 3-buffer ring
//      (2-ahead prefetch, 8 u-steps), slightly lower VGPR than r2's xa[4].
//   3. Single __syncthreads() after the main loop (before fixup+gather), so
//      divergent fixup time of different waves overlaps.
// All buffer indices are compile-time (template<G,CT> steps) — rule #20 safe.
// Layouts (verified): D col=lane&15, row=(lane>>4)*4+reg; A/B 8 contiguous k
// at k=8*(lane>>4). C = W(48x64) . X^T; OR-butterfly (16,32) assembles each
// row's 48-bit mask on its owner lane (row == lane within the 64-row group).

typedef float f32x2 __attribute__((ext_vector_type(2)));
typedef float f32x4 __attribute__((ext_vector_type(4)));
typedef short short8 __attribute__((ext_vector_type(8)));

static constexpr int   kBlocks  = 2048;            // x4 waves x128 rows = 1M rows
static constexpr float kTau     = 1.5f * 0x1p-24f; // f32 sigmoid dead-zone threshold
static constexpr float kMarginB = 8e-4f;           // 7x analytic worst-case bf16-split drift

// Bit-exact replica of numpy's baseline-SIMD einsum f32 order (r5-verified).
__device__ __noinline__ float np_exact_dot(const float* __restrict__ xs,
                                           const float* __restrict__ w) {
#pragma clang fp contract(off)
  float s[4];
#pragma unroll
  for (int L = 0; L < 4; ++L) {
    float t = xs[12 + L] * w[12 + L];
    t = xs[8 + L] * w[8 + L] + t;
    t = xs[4 + L] * w[4 + L] + t;
    t = xs[0 + L] * w[0 + L] + t;
#pragma unroll
    for (int j = 1; j < 4; ++j) {
      const int o = 16 * j;
      t = xs[o + 12 + L] * w[o + 12 + L] + t;
      t = xs[o +  8 + L] * w[o +  8 + L] + t;
      t = xs[o +  4 + L] * w[o +  4 + L] + t;
      t = xs[o +  0 + L] * w[o +  0 + L] + t;
    }
    s[L] = t;
  }
  return (s[0] + s[1]) + (s[2] + s[3]);   // SSE3 hadd pairing
}

__device__ __forceinline__ short bf16_hi(float v, float& hf) {
  const __hip_bfloat16 h = __float2bfloat16(v);   // RNE
  hf = __bfloat162float(h);
  return __builtin_bit_cast(short, h);
}
__device__ __forceinline__ short bf16_rn(float v) {
  return __builtin_bit_cast(short, __float2bfloat16(v));
}

// One 16-row x-tile: optional 2-ahead prefetch, bf16 split, 18 MFMA, masks,
// OR-butterfly; lane group q==CT keeps the assembled row masks.
template <int G, int CT>
__device__ __forceinline__ void step(const float* __restrict__ xb,
                                     f32x4 (&xa)[3][4],
                                     const short8 (&whi)[3][2],
                                     const short8 (&wlo)[3][2],
                                     const f32x4 (&taub)[3],
                                     int q, uint64_t& bits, uint64_t& flag) {
  constexpr int U = G * 4 + CT;
  if constexpr (U < 6) {           // 2-ahead prefetch into the ring
    const float* p = xb + (size_t)(U + 2) * 1024;
    xa[(U + 2) % 3][0] = *(const f32x4*)(p);
    xa[(U + 2) % 3][1] = *(const f32x4*)(p + 4);
    xa[(U + 2) % 3][2] = *(const f32x4*)(p + 32);
    xa[(U + 2) % 3][3] = *(const f32x4*)(p + 36);
  }
  constexpr int cb = U % 3;

  short8 xh0, xl0, xh1, xl1;
#pragma unroll
  for (int i = 0; i < 4; ++i) {
    float hf;
    short h = bf16_hi(xa[cb][0][i], hf); xh0[i]     = h; xl0[i]     = bf16_rn(xa[cb][0][i] - hf);
    h = bf16_hi(xa[cb][1][i], hf);       xh0[4 + i] = h; xl0[4 + i] = bf16_rn(xa[cb][1][i] - hf);
    h = bf16_hi(xa[cb][2][i], hf);       xh1[i]     = h; xl1[i]     = bf16_rn(xa[cb][2][i] - hf);
    h = bf16_hi(xa[cb][3][i], hf);       xh1[4 + i] = h; xl1[4 + i] = bf16_rn(xa[cb][3][i] - hf);
  }

  // 3 row-tiles x (2 k-halves x 3 split terms) = 18 MFMA; lo.lo dropped.
  f32x4 acc[3];
#pragma unroll
  for (int rt = 0; rt < 3; ++rt) {
    f32x4 c = {0.f, 0.f, 0.f, 0.f};
    c = __builtin_amdgcn_mfma_f32_16x16x32_bf16(whi[rt][0], xh0, c, 0, 0, 0);
    c = __builtin_amdgcn_mfma_f32_16x16x32_bf16(whi[rt][1], xh1, c, 0, 0, 0);
    c = __builtin_amdgcn_mfma_f32_16x16x32_bf16(whi[rt][0], xl0, c, 0, 0, 0);
    c = __builtin_amdgcn_mfma_f32_16x16x32_bf16(whi[rt][1], xl1, c, 0, 0, 0);
    c = __builtin_amdgcn_mfma_f32_16x16x32_bf16(wlo[rt][0], xh0, c, 0, 0, 0);
    c = __builtin_amdgcn_mfma_f32_16x16x32_bf16(wlo[rt][1], xh1, c, 0, 0, 0);
    acc[rt] = c;
  }

  uint64_t pb = 0, pf = 0;
#pragma unroll
  for (int rt = 0; rt < 3; ++rt) {
#pragma unroll
    for (int i = 0; i < 4; ++i) {
      const float t = acc[rt][i] - taub[rt][i];          // = z_hat - tau
      const int d = rt * 16 + q * 4 + i;
      pb |= (uint64_t)(t > 0.f ? 1u : 0u) << d;
      pf |= (uint64_t)(__builtin_fabsf(t) < kMarginB ? 1u : 0u) << d;
    }
  }
  pb |= __shfl_xor((unsigned long long)pb, 16);
  pb |= __shfl_xor((unsigned long long)pb, 32);
  pf |= __shfl_xor((unsigned long long)pf, 16);
  pf |= __shfl_xor((unsigned long long)pf, 32);
  if (CT == q) { bits = pb; flag = pf; }   // lane owns row CT*16+(lane&15)==lane
}

__global__ __launch_bounds__(256) void forest_mfma(
    const float* __restrict__ x,     // [B,64]
    const float* __restrict__ Wsel,  // [48,64]
    const float* __restrict__ bsel,  // [48]
    const float* __restrict__ leaf,  // [8,64,2]
    const float* __restrict__ fcw,   // [2,16]
    const float* __restrict__ fcb,   // [2]
    float* __restrict__ out)         // [B,2]
{
  const int lane = threadIdx.x & 63;
  const int wave = threadIdx.x >> 6;
  const int q    = lane >> 4;    // 0..3 : k-chunk group / d sub-offset
  const int r16  = lane & 15;    // 0..15
  const int rowbase = (blockIdx.x * 4 + wave) * 128;

  // ---- FIRST: issue x loads for u=0,1 (8 dwordx4 in flight). lleaf staging,
  //      W load+convert and taub all execute under this HBM latency.
  const float* xb = x + (size_t)(rowbase + r16) * 64 + q * 8;
  f32x4 xa[3][4];
#pragma unroll
  for (int c = 0; c < 2; ++c) {
    const float* p = xb + (size_t)c * 1024;
    xa[c][0] = *(const f32x4*)(p);
    xa[c][1] = *(const f32x4*)(p + 4);
    xa[c][2] = *(const f32x4*)(p + 32);
    xa[c][3] = *(const f32x4*)(p + 36);
  }

  __shared__ f32x2 lleaf[512];
  ((f32x4*)lleaf)[threadIdx.x] = ((const f32x4*)leaf)[threadIdx.x];
  // (sync deferred to just before the epilogue gather)

  // ---- W fragments (A-operand), split hi/lo bf16. Lane: row=rt*16+r16,
  //      k = kh*32 + q*8 + i. Amortized over 128 rows now.
  short8 whi[3][2], wlo[3][2];
#pragma unroll
  for (int rt = 0; rt < 3; ++rt) {
#pragma unroll
    for (int kh = 0; kh < 2; ++kh) {
      const float* wp = Wsel + (rt * 16 + r16) * 64 + kh * 32 + q * 8;
      const f32x4 w0 = *(const f32x4*)wp;
      const f32x4 w1 = *(const f32x4*)(wp + 4);
      short8 hi, lo;
#pragma unroll
      for (int i = 0; i < 4; ++i) {
        float hf;
        short h = bf16_hi(w0[i], hf);
        hi[i] = h;     lo[i]     = bf16_rn(w0[i] - hf);
        h = bf16_hi(w1[i], hf);
        hi[4 + i] = h; lo[4 + i] = bf16_rn(w1[i] - hf);
      }
      whi[rt][kh] = hi; wlo[rt][kh] = lo;
    }
  }

  // ---- tau - bias for this lane's 12 d's: d = rt*16 + q*4 + i
  f32x4 taub[3];
#pragma unroll
  for (int rt = 0; rt < 3; ++rt) {
    const f32x4 bs = *(const f32x4*)(bsel + rt * 16 + q * 4);
    f32x4 t;
#pragma unroll
    for (int i = 0; i < 4; ++i) t[i] = kTau - bs[i];
    taub[rt] = t;
  }

  // ---- Main loop: 2 groups x 4 col-tiles = 8 u-steps, 3-buffer ring.
  uint64_t bits0 = 0, flag0 = 0, bits1 = 0, flag1 = 0;
  step<0, 0>(xb, xa, whi, wlo, taub, q, bits0, flag0);
  step<0, 1>(xb, xa, whi, wlo, taub, q, bits0, flag0);
  step<0, 2>(xb, xa, whi, wlo, taub, q, bits0, flag0);
  step<0, 3>(xb, xa, whi, wlo, taub, q, bits0, flag0);
  step<1, 0>(xb, xa, whi, wlo, taub, q, bits1, flag1);
  step<1, 1>(xb, xa, whi, wlo, taub, q, bits1, flag1);
  step<1, 2>(xb, xa, whi, wlo, taub, q, bits1, flag1);
  step<1, 3>(xb, xa, whi, wlo, taub, q, bits1, flag1);

  __syncthreads();   // lleaf staged in prologue; fixup below is divergent, so
                     // sync FIRST and let slow-fixup waves run independently.

  // ---- Divergent fixup: bit-exact np-order recompute of flagged logits only.
  {
    const float* __restrict__ xrow = x + (size_t)(rowbase + lane) * 64;
    while (flag0) {
      const int d = __builtin_ctzll(flag0);
      flag0 &= flag0 - 1;
      const float z = np_exact_dot(xrow, Wsel + d * 64) + bsel[d];
      const uint64_t m = 1ull << d;
      bits0 = (z > kTau) ? (bits0 | m) : (bits0 & ~m);
    }
    const float* __restrict__ xrow1 = xrow + 64 * 64;
    while (flag1) {
      const int d = __builtin_ctzll(flag1);
      flag1 &= flag1 - 1;
      const float z = np_exact_dot(xrow1, Wsel + d * 64) + bsel[d];
      const uint64_t m = 1ull << d;
      bits1 = (z > kTau) ? (bits1 | m) : (bits1 & ~m);
    }
  }

  // ---- Tree walk (level 0 = MSB), LDS leaf gather, 16->2 FC, both groups.
  const float fb0 = fcb[0], fb1 = fcb[1];
#pragma unroll
  for (int g = 0; g < 2; ++g) {
    const uint64_t bits = g ? bits1 : bits0;
    float o0 = fb0, o1 = fb1;
#pragma unroll
    for (int t = 0; t < 8; ++t) {
      int idx = 0;
#pragma unroll
      for (int l = 0; l < 6; ++l)
        idx = idx * 2 + (int)((bits >> (t * 6 + l)) & 1u);
      const f32x2 lv = lleaf[t * 64 + idx];
      o0 = fmaf(lv.x, fcw[2 * t], o0);
      o0 = fmaf(lv.y, fcw[2 * t + 1], o0);
      o1 = fmaf(lv.x, fcw[16 + 2 * t], o1);
      o1 = fmaf(lv.y, fcw[16 + 2 * t + 1], o1);
    }
    f32x2 r; r.x = o0; r.y = o1;
    ((f32x2*)out)[rowbase + g * 64 + lane] = r;
  }
}

extern "C" void kernel_launch(void* const* d_in, const int* in_sizes, int n_in,
                              void* d_out, int out_size, void* d_ws, size_t ws_size,
                              hipStream_t stream) {
  (void)in_sizes; (void)n_in; (void)out_size; (void)d_ws; (void)ws_size;
  forest_mfma<<<kBlocks, 256, 0, stream>>>(
      (const float*)d_in[0],   // x
      (const float*)d_in[1],   // W_sel
      (const float*)d_in[2],   // b_sel
      (const float*)d_in[3],   // leaf_values
      (const float*)d_in[4],   // fc_w
      (const float*)d_in[5],   // fc_b
      (float*)d_out);
}